// Round 4
// baseline (264.104 us; speedup 1.0000x reference)
//
#include <hip/hip_runtime.h>

// MinEuclideanDistBlock: x(32,8,4096) f32, shapelets(8,128,64) f32 -> out(32,1,128) f32
// out[b,k] = min_w sum_c sqrt( xnorm[b,c,w] + snorm[c,k] - 2*sum_s x[b,c,w+s]*h[c,k,s] )
//
// R3 -> R4 (post-mortem: VALUBusy 29%, MfmaUtil 10%, occ 17.6% -> latency-bound):
//  - __launch_bounds__(256,4): 4 blocks/CU (4 independent barrier groups to overlap).
//  - Bs staging software-pipelined: c+1's hbf tile prefetched into regs during
//    compute(c); stage phase is reg->LDS only (global latency hidden).
//  - block-level LDS min before global atomicMin (512 -> 128 atomics/block).

typedef short short8 __attribute__((ext_vector_type(8)));
typedef float f32x4 __attribute__((ext_vector_type(4)));

constexpr int Bn = 32, Cn = 8, Ln = 4096, Kn = 128, Sn = 64;
constexpr int Wn = Ln - Sn + 1;          // 4033
constexpr int WT = 128;                  // windows per block
constexpr int NWT = (Wn + WT - 1) / WT;  // 32
constexpr int BDIM = 256;

__device__ __forceinline__ unsigned int f2bf(float f) {
  unsigned int u = __float_as_uint(f);
  u += 0x7FFFu + ((u >> 16) & 1u);       // round-to-nearest-even
  return u >> 16;
}

// ws layout: [0, 128KB): ushort hbf[C][K][S] = bf16(-2*h);  [128KB, +4KB): float snorm[C][K]
__global__ void prep_kernel(const float* __restrict__ sh,
                            unsigned int* __restrict__ out,
                            unsigned short* __restrict__ hbf,
                            float* __restrict__ snorm) {
  int gid = blockIdx.x * blockDim.x + threadIdx.x;  // 0..4095
  out[gid] = 0x7F7FFFFFu;                           // FLT_MAX bits (Bn*Kn == 4096)
  if (gid < Cn * Kn) {
    const float4* row = (const float4*)(sh + (size_t)gid * Sn);
    uint2* orow = (uint2*)(hbf + (size_t)gid * Sn);
    float a = 0.f;
    #pragma unroll
    for (int i = 0; i < 16; ++i) {
      float4 v = row[i];
      a += v.x * v.x + v.y * v.y + v.z * v.z + v.w * v.w;
      unsigned int p0 = f2bf(-2.f * v.x) | (f2bf(-2.f * v.y) << 16);
      unsigned int p1 = f2bf(-2.f * v.z) | (f2bf(-2.f * v.w) << 16);
      orow[i] = make_uint2(p0, p1);
    }
    snorm[gid] = a;
  }
}

__launch_bounds__(BDIM, 4)
__global__ void med_kernel(const float* __restrict__ x,
                           const unsigned short* __restrict__ hbf,
                           const float* __restrict__ snorm,
                           unsigned int* __restrict__ out) {
  constexpr int XRS = 200;  // Xr row stride (elems); 400B, 16B-aligned rows
  constexpr int BSS = 80;   // Bs row stride (elems); 160B = 40 words (8 mod 32)
  __shared__ __align__(16) unsigned short Xr[8 * XRS];
  __shared__ __align__(16) unsigned short Bs[Kn * BSS];
  __shared__ __align__(16) float xnormC[Cn * WT];
  __shared__ __align__(16) float snormC[Cn * Kn];
  __shared__ unsigned int smin[Kn];

  const int tid  = threadIdx.x;
  const int b    = blockIdx.y;
  const int w0   = blockIdx.x * WT;
  const int lane = tid & 63;
  const int wv   = tid >> 6;     // wave 0..3
  const int quad = lane >> 4;    // 0..3
  const int n16  = lane & 15;
  const int wbase = wv * 32;     // this wave's window offset in tile

  const float* xb = x + (size_t)b * Cn * Ln;

  // snorm: one float4 per thread from prep output
  ((float4*)snormC)[tid] = ((const float4*)snorm)[tid];
  if (tid < Kn) smin[tid] = 0x7F7FFFFFu;

  // xnorm: 256 threads = 8c x 32 groups, 4 windows each (rolling update), fp32-exact
  {
    int c  = tid >> 5;
    int m0 = (tid & 31) * 4;
    const float* xc = xb + c * Ln;
    auto xq = [&](int i) -> float {
      float v = (i < Ln) ? xc[i] : 0.f;
      return v * v;
    };
    float s0 = 0.f;
    for (int s = 0; s < Sn; ++s) s0 += xq(w0 + m0 + s);
    float s1 = s0 - xq(w0 + m0 + 0) + xq(w0 + m0 + 64);
    float s2 = s1 - xq(w0 + m0 + 1) + xq(w0 + m0 + 65);
    float s3 = s2 - xq(w0 + m0 + 2) + xq(w0 + m0 + 66);
    xnormC[c * WT + m0 + 0] = s0;
    xnormC[c * WT + m0 + 1] = s1;
    xnormC[c * WT + m0 + 2] = s2;
    xnormC[c * WT + m0 + 3] = s3;
  }

  // ---- B-prefetch pipeline state: channel 0 tile -> regs ----
  const uint4* hb4 = (const uint4*)hbf;   // per c: 1024 uint4
  const int bk = tid >> 3, bch = tid & 7; // this thread's 4 Bs row-chunks (k, k+32, ...)
  uint4 Breg[4];
  #pragma unroll
  for (int rep = 0; rep < 4; ++rep) Breg[rep] = hb4[tid + rep * BDIM];

  float dist[2][8][4] = {};  // [mtile][ntile2][reg] summed distance over c

  for (int c = 0; c < Cn; ++c) {
    __syncthreads();  // consumers of LDS(c-1) done (also covers preamble writes)

    // ---- x loads issued first (latency partially hidden under B-writes) ----
    const float* xc = xb + c * Ln;
    float xf[3][2];
    int pid0 = tid;
    #pragma unroll
    for (int rep = 0; rep < 3; ++rep) {
      int pid = tid + rep * BDIM;         // 0..767
      int r = pid / 96;
      int p = pid - r * 96;               // pair index -> elems 2p, 2p+1 of row r
      int i0 = w0 + r + 2 * p;
      xf[rep][0] = (i0 < Ln) ? xc[i0] : 0.f;
      xf[rep][1] = (i0 + 1 < Ln) ? xc[i0 + 1] : 0.f;
    }
    // ---- Bs from prefetched regs ----
    #pragma unroll
    for (int rep = 0; rep < 4; ++rep)
      *(uint4*)(&Bs[(bk + rep * 32) * BSS + bch * 8]) = Breg[rep];
    // ---- x convert + write ----
    #pragma unroll
    for (int rep = 0; rep < 3; ++rep) {
      int pid = tid + rep * BDIM;
      int r = pid / 96;
      int p = pid - r * 96;
      *(unsigned int*)(&Xr[r * XRS + 2 * p]) = f2bf(xf[rep][0]) | (f2bf(xf[rep][1]) << 16);
    }
    (void)pid0;
    __syncthreads();

    // ---- prefetch next channel's B tile (lands during compute below) ----
    if (c < Cn - 1) {
      #pragma unroll
      for (int rep = 0; rep < 4; ++rep)
        Breg[rep] = hb4[(c + 1) * 1024 + tid + rep * BDIM];
    }

    // xnorm for this wave's 32 windows (C/D row = quad*4+reg) — one b128 each
    float4 xn[2];
    #pragma unroll
    for (int mt = 0; mt < 2; ++mt)
      xn[mt] = *(const float4*)(&xnormC[c * WT + wbase + mt * 16 + quad * 4]);

    // A fragments: lane m = n16, k = quad*8+j (+ks*32); one aligned b128 each
    short8 af[2][2];
    #pragma unroll
    for (int mt = 0; mt < 2; ++mt)
      #pragma unroll
      for (int ks = 0; ks < 2; ++ks) {
        int i = wbase + mt * 16 + n16 + ks * 32 + quad * 8;
        af[mt][ks] = *(const short8*)(&Xr[(i & 7) * XRS + (i >> 3) * 8]);
      }

    #pragma unroll
    for (int pass = 0; pass < 2; ++pass) {
      short8 bfr[4][2];
      float sn[4];
      #pragma unroll
      for (int nt = 0; nt < 4; ++nt) {
        int ksh = pass * 64 + nt * 16 + n16;
        sn[nt] = snormC[c * Kn + ksh];
        #pragma unroll
        for (int ks = 0; ks < 2; ++ks)
          bfr[nt][ks] = *(const short8*)(&Bs[ksh * BSS + ks * 32 + quad * 8]);
      }
      #pragma unroll
      for (int mt = 0; mt < 2; ++mt)
        #pragma unroll
        for (int nt = 0; nt < 4; ++nt) {
          f32x4 acc;
          #pragma unroll
          for (int rg = 0; rg < 4; ++rg) acc[rg] = xn[mt][rg] + sn[nt];
          acc = __builtin_amdgcn_mfma_f32_16x16x32_bf16(af[mt][0], bfr[nt][0], acc, 0, 0, 0);
          acc = __builtin_amdgcn_mfma_f32_16x16x32_bf16(af[mt][1], bfr[nt][1], acc, 0, 0, 0);
          // acc == d2 (norms preloaded in C, -2 folded into B)
          #pragma unroll
          for (int rg = 0; rg < 4; ++rg)
            dist[mt][pass * 4 + nt][rg] += __builtin_amdgcn_sqrtf(acc[rg]);
        }
    }
  }

  // ---- min over windows: lane -> wave -> block(LDS) -> global ----
  const int wql = w0 + wbase + quad * 4;
  #pragma unroll
  for (int nt2 = 0; nt2 < 8; ++nt2) {
    float v = 3.4e38f;
    #pragma unroll
    for (int mt = 0; mt < 2; ++mt)
      #pragma unroll
      for (int rg = 0; rg < 4; ++rg) {
        int wg = wql + mt * 16 + rg;
        float d = (wg < Wn) ? dist[mt][nt2][rg] : 3.4e38f;
        v = fminf(v, d);
      }
    v = fminf(v, __shfl_xor(v, 16, 64));
    v = fminf(v, __shfl_xor(v, 32, 64));
    if (lane < 16)
      atomicMin(&smin[nt2 * 16 + n16], __float_as_uint(v));
  }
  __syncthreads();
  if (tid < Kn)
    atomicMin(&out[b * Kn + tid], smin[tid]);
}

extern "C" void kernel_launch(void* const* d_in, const int* in_sizes, int n_in,
                              void* d_out, int out_size, void* d_ws, size_t ws_size,
                              hipStream_t stream) {
  const float* x  = (const float*)d_in[0];
  const float* sh = (const float*)d_in[1];
  unsigned int* out = (unsigned int*)d_out;
  unsigned short* hbf = (unsigned short*)d_ws;                  // 128 KB
  float* snorm = (float*)((char*)d_ws + (size_t)Cn * Kn * Sn * 2);  // +4 KB
  hipLaunchKernelGGL(prep_kernel, dim3(16), dim3(256), 0, stream, sh, out, hbf, snorm);
  hipLaunchKernelGGL(med_kernel, dim3(NWT, Bn), dim3(BDIM), 0, stream, x, hbf, snorm, out);
}

// Round 5
// 146.598 us; speedup vs baseline: 1.8016x; 1.8016x over previous
//
#include <hip/hip_runtime.h>

// MinEuclideanDistBlock: x(32,8,4096) f32, shapelets(8,128,64) f32 -> out(32,1,128) f32
// out[b,k] = min_w sum_c sqrt( xnorm[b,c,w] + snorm[c,k] - 2*sum_s x[b,c,w+s]*h[c,k,s] )
//
// R4 -> R5 (post-mortem: launch_bounds(256,4) caused VGPR 64 + 877MB scratch spill):
//  - occupancy via smaller footprint: K split across 2 blocks (grid 32x32x2),
//    each block 128w x 64k -> dist 32 regs, Bs 10KB, LDS ~19.5KB total.
//  - __launch_bounds__(256,3): cap ~170 VGPRs (headroom, no spill), 3 blocks/CU.
//  - BOTH x and B tiles prefetched to regs during compute(c-1); stage phase is
//    pure reg->LDS (R4 only prefetched B; x global latency was still exposed).

typedef short short8 __attribute__((ext_vector_type(8)));
typedef float f32x4 __attribute__((ext_vector_type(4)));

constexpr int Bn = 32, Cn = 8, Ln = 4096, Kn = 128, Sn = 64;
constexpr int Wn = Ln - Sn + 1;          // 4033
constexpr int WT = 128;                  // windows per block
constexpr int KT = 64;                   // shapelets per block (K split in 2)
constexpr int NWT = (Wn + WT - 1) / WT;  // 32
constexpr int BDIM = 256;

__device__ __forceinline__ unsigned int f2bf(float f) {
  unsigned int u = __float_as_uint(f);
  u += 0x7FFFu + ((u >> 16) & 1u);       // round-to-nearest-even
  return u >> 16;
}

// ws layout: [0, 128KB): ushort hbf[C][K][S] = bf16(-2*h);  [128KB, +4KB): float snorm[C][K]
__global__ void prep_kernel(const float* __restrict__ sh,
                            unsigned int* __restrict__ out,
                            unsigned short* __restrict__ hbf,
                            float* __restrict__ snorm) {
  int gid = blockIdx.x * blockDim.x + threadIdx.x;  // 0..4095
  out[gid] = 0x7F7FFFFFu;                           // FLT_MAX bits (Bn*Kn == 4096)
  if (gid < Cn * Kn) {
    const float4* row = (const float4*)(sh + (size_t)gid * Sn);
    uint2* orow = (uint2*)(hbf + (size_t)gid * Sn);
    float a = 0.f;
    #pragma unroll
    for (int i = 0; i < 16; ++i) {
      float4 v = row[i];
      a += v.x * v.x + v.y * v.y + v.z * v.z + v.w * v.w;
      unsigned int p0 = f2bf(-2.f * v.x) | (f2bf(-2.f * v.y) << 16);
      unsigned int p1 = f2bf(-2.f * v.z) | (f2bf(-2.f * v.w) << 16);
      orow[i] = make_uint2(p0, p1);
    }
    snorm[gid] = a;
  }
}

__launch_bounds__(BDIM, 3)
__global__ void med_kernel(const float* __restrict__ x,
                           const unsigned short* __restrict__ hbf,
                           const float* __restrict__ snorm,
                           unsigned int* __restrict__ out) {
  constexpr int XRS = 200;  // Xr row stride (elems); 400B, 16B-aligned rows
  constexpr int BSS = 80;   // Bs row stride (elems); 160B = 40 words (8 mod 32)
  __shared__ __align__(16) unsigned short Xr[8 * XRS];      // 3.2 KB
  __shared__ __align__(16) unsigned short Bs[KT * BSS];     // 10 KB
  __shared__ __align__(16) float xnormC[Cn * WT];           // 4 KB
  __shared__ __align__(16) float snormC[Cn * KT];           // 2 KB
  __shared__ unsigned int smin[KT];

  const int tid  = threadIdx.x;
  const int b    = blockIdx.y;
  const int w0   = blockIdx.x * WT;
  const int kh0  = blockIdx.z * KT;      // this block's shapelet half
  const int lane = tid & 63;
  const int wv   = tid >> 6;     // wave 0..3
  const int quad = lane >> 4;    // 0..3
  const int n16  = lane & 15;
  const int wbase = wv * 32;     // this wave's window offset in tile

  const float* xb = x + (size_t)b * Cn * Ln;
  const uint4* hb4 = (const uint4*)hbf;  // global uint4 idx for (c,k,ch): (c*Kn+k)*8 + ch

  // ---- prefetch channel 0 tiles into regs (lands under the preamble) ----
  uint4 Breg[2];
  #pragma unroll
  for (int rep = 0; rep < 2; ++rep)
    Breg[rep] = hb4[(size_t)kh0 * 8 + tid + rep * BDIM];
  float xf[3][2];
  #pragma unroll
  for (int rep = 0; rep < 3; ++rep) {
    int pid = tid + rep * BDIM;          // 0..767
    int r = pid / 96;
    int p = pid - r * 96;                // pair -> elems 2p, 2p+1 of shifted row r
    int i0 = w0 + r + 2 * p;
    xf[rep][0] = (i0 < Ln) ? xb[i0] : 0.f;
    xf[rep][1] = (i0 + 1 < Ln) ? xb[i0 + 1] : 0.f;
  }

  // snorm: this block's half, one float4 per thread (tid<128)
  if (tid < 128) {
    int c = tid >> 4, j = tid & 15;
    ((float4*)snormC)[tid] = ((const float4*)snorm)[c * (Kn / 4) + kh0 / 4 + j];
  }
  if (tid < KT) smin[tid] = 0x7F7FFFFFu;

  // xnorm: 256 threads = 8c x 32 groups, 4 windows each (rolling update), fp32-exact
  {
    int c  = tid >> 5;
    int m0 = (tid & 31) * 4;
    const float* xc = xb + c * Ln;
    auto xq = [&](int i) -> float {
      float v = (i < Ln) ? xc[i] : 0.f;
      return v * v;
    };
    float s0 = 0.f;
    for (int s = 0; s < Sn; ++s) s0 += xq(w0 + m0 + s);
    float s1 = s0 - xq(w0 + m0 + 0) + xq(w0 + m0 + 64);
    float s2 = s1 - xq(w0 + m0 + 1) + xq(w0 + m0 + 65);
    float s3 = s2 - xq(w0 + m0 + 2) + xq(w0 + m0 + 66);
    xnormC[c * WT + m0 + 0] = s0;
    xnormC[c * WT + m0 + 1] = s1;
    xnormC[c * WT + m0 + 2] = s2;
    xnormC[c * WT + m0 + 3] = s3;
  }

  const int bk = tid >> 3, bch = tid & 7;  // Bs staging coords (rows bk, bk+32)
  float dist[2][4][4] = {};                // [mtile][ntile][reg] summed over c

  for (int c = 0; c < Cn; ++c) {
    // pack x pairs (VALU, pre-barrier; load waitcnt lands here, under prior compute)
    unsigned int xp[3];
    #pragma unroll
    for (int rep = 0; rep < 3; ++rep)
      xp[rep] = f2bf(xf[rep][0]) | (f2bf(xf[rep][1]) << 16);

    __syncthreads();  // consumers of LDS(c-1) done (also covers preamble writes)

    // ---- stage phase: pure reg -> LDS ----
    *(uint4*)(&Bs[bk * BSS + bch * 8]) = Breg[0];
    *(uint4*)(&Bs[(bk + 32) * BSS + bch * 8]) = Breg[1];
    #pragma unroll
    for (int rep = 0; rep < 3; ++rep) {
      int pid = tid + rep * BDIM;
      int r = pid / 96;
      int p = pid - r * 96;
      *(unsigned int*)(&Xr[r * XRS + 2 * p]) = xp[rep];
    }
    __syncthreads();

    // ---- prefetch next channel's tiles (lands during compute below) ----
    if (c < Cn - 1) {
      const float* xc = xb + (c + 1) * Ln;
      #pragma unroll
      for (int rep = 0; rep < 2; ++rep)
        Breg[rep] = hb4[((size_t)(c + 1) * Kn + kh0) * 8 + tid + rep * BDIM];
      #pragma unroll
      for (int rep = 0; rep < 3; ++rep) {
        int pid = tid + rep * BDIM;
        int r = pid / 96;
        int p = pid - r * 96;
        int i0 = w0 + r + 2 * p;
        xf[rep][0] = (i0 < Ln) ? xc[i0] : 0.f;
        xf[rep][1] = (i0 + 1 < Ln) ? xc[i0 + 1] : 0.f;
      }
    }

    // xnorm for this wave's 32 windows (C/D row = quad*4+reg) — one b128 each
    float4 xn[2];
    #pragma unroll
    for (int mt = 0; mt < 2; ++mt)
      xn[mt] = *(const float4*)(&xnormC[c * WT + wbase + mt * 16 + quad * 4]);

    // A fragments: lane m = n16, k = quad*8+j (+ks*32); one aligned b128 each
    short8 af[2][2];
    #pragma unroll
    for (int mt = 0; mt < 2; ++mt)
      #pragma unroll
      for (int ks = 0; ks < 2; ++ks) {
        int i = wbase + mt * 16 + n16 + ks * 32 + quad * 8;
        af[mt][ks] = *(const short8*)(&Xr[(i & 7) * XRS + (i >> 3) * 8]);
      }

    short8 bfr[4][2];
    float sn[4];
    #pragma unroll
    for (int nt = 0; nt < 4; ++nt) {
      int ksh = nt * 16 + n16;           // local shapelet row 0..63
      sn[nt] = snormC[c * KT + ksh];
      #pragma unroll
      for (int ks = 0; ks < 2; ++ks)
        bfr[nt][ks] = *(const short8*)(&Bs[ksh * BSS + ks * 32 + quad * 8]);
    }
    #pragma unroll
    for (int mt = 0; mt < 2; ++mt)
      #pragma unroll
      for (int nt = 0; nt < 4; ++nt) {
        f32x4 acc;
        #pragma unroll
        for (int rg = 0; rg < 4; ++rg) acc[rg] = xn[mt][rg] + sn[nt];
        acc = __builtin_amdgcn_mfma_f32_16x16x32_bf16(af[mt][0], bfr[nt][0], acc, 0, 0, 0);
        acc = __builtin_amdgcn_mfma_f32_16x16x32_bf16(af[mt][1], bfr[nt][1], acc, 0, 0, 0);
        // acc == d2 (norms preloaded in C, -2 folded into B)
        #pragma unroll
        for (int rg = 0; rg < 4; ++rg)
          dist[mt][nt][rg] += __builtin_amdgcn_sqrtf(acc[rg]);
      }
  }

  // ---- min over windows: lane -> wave -> block(LDS) -> global ----
  const int wql = w0 + wbase + quad * 4;
  #pragma unroll
  for (int nt = 0; nt < 4; ++nt) {
    float v = 3.4e38f;
    #pragma unroll
    for (int mt = 0; mt < 2; ++mt)
      #pragma unroll
      for (int rg = 0; rg < 4; ++rg) {
        int wg = wql + mt * 16 + rg;
        float d = (wg < Wn) ? dist[mt][nt][rg] : 3.4e38f;
        v = fminf(v, d);
      }
    v = fminf(v, __shfl_xor(v, 16, 64));
    v = fminf(v, __shfl_xor(v, 32, 64));
    if (lane < 16)
      atomicMin(&smin[nt * 16 + n16], __float_as_uint(v));
  }
  __syncthreads();
  if (tid < KT)
    atomicMin(&out[b * Kn + kh0 + tid], smin[tid]);
}

extern "C" void kernel_launch(void* const* d_in, const int* in_sizes, int n_in,
                              void* d_out, int out_size, void* d_ws, size_t ws_size,
                              hipStream_t stream) {
  const float* x  = (const float*)d_in[0];
  const float* sh = (const float*)d_in[1];
  unsigned int* out = (unsigned int*)d_out;
  unsigned short* hbf = (unsigned short*)d_ws;                  // 128 KB
  float* snorm = (float*)((char*)d_ws + (size_t)Cn * Kn * Sn * 2);  // +4 KB
  hipLaunchKernelGGL(prep_kernel, dim3(16), dim3(256), 0, stream, sh, out, hbf, snorm);
  hipLaunchKernelGGL(med_kernel, dim3(NWT, Bn, 2), dim3(BDIM), 0, stream, x, hbf, snorm, out);
}